// Round 3
// baseline (208.877 us; speedup 1.0000x reference)
//
#include <hip/hip_runtime.h>

// pred/target (4,4,64,128,128) fp32 -> 16 volumes of 64x128x128.
#define NB 16
#define DD 64
#define HH 128
#define WW 128
#define HW (HH * WW)

constexpr int TH = 8;                  // output rows per block
constexpr int LY = TH + 2;             // 10 input rows
constexpr int PL = LY * WW;            // LDS plane-slot stride (floats) = 1280
constexpr int RING = 8;                // plane ring slots -> 40960 B LDS
constexpr int NT = 8;                  // tiles per quarter (2 output planes each)
constexpr int NQ = 4;                  // d-quarters per volume (4*16 = 64 planes)
constexpr int SLOTS = 3;               // 640 float4 positions / 256 threads (last half-populated)
constexpr float INV_COUNT = 1.0f / 50331648.0f; // 1/(3*16*64*128*128)

__global__ void zero_out_kernel(float* out) {
    if (threadIdx.x == 0 && blockIdx.x == 0) out[0] = 0.0f;
}

struct Part { float4 A, Bh, Bw; };     // per-plane row partials (held in regs)

__global__ __launch_bounds__(256, 3) void sobel_l1_kernel(
    const float* __restrict__ pred,
    const float* __restrict__ target,
    float* __restrict__ out)
{
    // 8-slot plane ring: each input plane staged to LDS exactly once per
    // quarter. Plane p lives in slot (p+1)%8. Tile tau computes NEW plane
    // partials for planes 2t+1, 2t+2 (slots (2t+2..2t+3)%8) while planes
    // 2t+3, 2t+4 prefetch into slots (2t+4..2t+5)%8 -- disjoint, one
    // barrier per tile. Partials for the previous two planes are kept in
    // REGISTERS (P0..P3 ring), so each LDS element is read 3x (row halo)
    // instead of 6x, and per-tile plane math is halved.
    __shared__ float ring[RING * PL];  // 40960 B

    const int tid = threadIdx.x;
    int b = blockIdx.x;                // 1024 blocks: 16 bh x 4 quarter x 16 bn
    const int bh = b & 15; b >>= 4;
    const int q  = b & 3;  b >>= 2;
    const int bn = b;

    const int h0 = bh * TH;
    const int dbase = q * (NT * 2);                // 0, 16, 32, 48
    const size_t nbase = (size_t)bn * (size_t)(DD * HW);

    // ---- per-slot staging constants: 640 float4 positions over 256 threads ----
    const bool k2ok = tid < 128;
    int  soff[SLOTS];   // clamped-row load offset within plane
    int  stoff[SLOTS];  // unclamped LDS store offset within plane slot
    int  sz[SLOTS];     // which new plane (0/1)
    bool sokh[SLOTS];   // row in range
#pragma unroll
    for (int k = 0; k < SLOTS; ++k) {
        const int i  = (k < 2) ? (k * 256 + tid) : (512 + (tid & 127));
        const int z  = i / 320;
        const int r  = i - z * 320;
        const int y  = r >> 5;
        const int q4 = r & 31;
        const int gh = h0 - 1 + y;
        sokh[k]  = (unsigned)gh < HH;
        soff[k]  = min(max(gh, 0), HH - 1) * WW + 4 * q4;
        stoff[k] = y * WW + 4 * q4;
        sz[k]    = z;
    }

    float4 sp[SLOTS], sq[SLOTS];       // raw staging (subtract deferred to store)

    auto load_pair = [&](int p0) {     // issue loads for planes p0, p0+1
#pragma unroll
        for (int k = 0; k < SLOTS; ++k) {
            if (k < 2 || k2ok) {
                const int gd  = dbase + p0 + sz[k];
                const int gdc = min(max(gd, 0), DD - 1);
                const size_t idx = nbase + (size_t)gdc * HW + soff[k];
                sp[k] = *(const float4*)(pred + idx);
                sq[k] = *(const float4*)(target + idx);
            }
        }
    };

    auto store_pair = [&](int p0) {    // (pred-target)*mask -> ring slots
        const int base0 = ((p0 + 1) % RING) * PL;
        const int base1 = ((p0 + 2) % RING) * PL;
#pragma unroll
        for (int k = 0; k < SLOTS; ++k) {
            if (k < 2 || k2ok) {
                const int gd = dbase + p0 + sz[k];
                const float m = (sokh[k] && (unsigned)gd < DD) ? 1.0f : 0.0f;
                float* dst = &ring[(sz[k] ? base1 : base0) + stoff[k]];
                *(float4*)dst = float4{(sp[k].x - sq[k].x) * m,
                                       (sp[k].y - sq[k].y) * m,
                                       (sp[k].z - sq[k].z) * m,
                                       (sp[k].w - sq[k].w) * m};
            }
        }
    };

    const int tc = tid & 31;           // w-quad
    const int lh = tid >> 5;           // output row in tile

    // Compute row partials for one plane from LDS: A = s(h)s(w)v,
    // Bh = d(h)s(w)v, Bw = s(h)d(w)v. All 3 ds_read_b128 issued up front.
    auto make_partial = [&](int slot, Part& P) {
        const int base = slot * PL + lh * WW + 4 * tc;
        const float4 v0 = *(const float4*)&ring[base];
        const float4 v1 = *(const float4*)&ring[base + WW];
        const float4 v2 = *(const float4*)&ring[base + 2 * WW];
        float4 rs[3], rdw[3];
        const float4 vv[3] = {v0, v1, v2};
#pragma unroll
        for (int r = 0; r < 3; ++r) {
            const float4 v = vv[r];
            float lm = __shfl_up(v.w, 1, 32);
            float rp = __shfl_down(v.x, 1, 32);
            if (tc == 0)  lm = 0.f;
            if (tc == 31) rp = 0.f;
            rs[r]  = float4{lm  + 2.f * v.x + v.y,
                            v.x + 2.f * v.y + v.z,
                            v.y + 2.f * v.z + v.w,
                            v.z + 2.f * v.w + rp};
            rdw[r] = float4{v.y - lm, v.z - v.x, v.w - v.y, rp - v.z};
        }
        P.A  = float4{rs[0].x + 2.f * rs[1].x + rs[2].x,
                      rs[0].y + 2.f * rs[1].y + rs[2].y,
                      rs[0].z + 2.f * rs[1].z + rs[2].z,
                      rs[0].w + 2.f * rs[1].w + rs[2].w};
        P.Bh = float4{rs[2].x - rs[0].x, rs[2].y - rs[0].y,
                      rs[2].z - rs[0].z, rs[2].w - rs[0].w};
        P.Bw = float4{rdw[0].x + 2.f * rdw[1].x + rdw[2].x,
                      rdw[0].y + 2.f * rdw[1].y + rdw[2].y,
                      rdw[0].z + 2.f * rdw[1].z + rdw[2].z,
                      rdw[0].w + 2.f * rdw[1].w + rdw[2].w};
    };

    float acc = 0.0f;
    auto combine = [&](const Part& Q0, const Part& Q1, const Part& Q2) {
        const float4 a0 = Q0.A,  a2 = Q2.A;
        const float4 b0 = Q0.Bh, b1 = Q1.Bh, b2 = Q2.Bh;
        const float4 c0 = Q0.Bw, c1 = Q1.Bw, c2 = Q2.Bw;
        acc += fabsf(a2.x - a0.x) + fabsf(a2.y - a0.y)
             + fabsf(a2.z - a0.z) + fabsf(a2.w - a0.w);
        acc += fabsf(b0.x + 2.f * b1.x + b2.x) + fabsf(b0.y + 2.f * b1.y + b2.y)
             + fabsf(b0.z + 2.f * b1.z + b2.z) + fabsf(b0.w + 2.f * b1.w + b2.w);
        acc += fabsf(c0.x + 2.f * c1.x + c2.x) + fabsf(c0.y + 2.f * c1.y + c2.y)
             + fabsf(c0.z + 2.f * c1.z + c2.z) + fabsf(c0.w + 2.f * c1.w + c2.w);
    };

    // ---- prologue: stage planes -1,0,1,2 into slots 0..3; partials -1,0 ----
    load_pair(-1); store_pair(-1);     // slots 0,1
    load_pair(1);  store_pair(1);      // slots 2,3
    __syncthreads();

    Part P0, P1, P2, P3;               // reg ring: plane p -> P[(p+1)%4]
    make_partial(0, P0);               // plane -1
    make_partial(1, P1);               // plane  0

    // ---- main loop: 2 x fully-unrolled 4-tile body (period of both rings) ----
    for (int tj = 0; tj < 2; ++tj) {
#pragma unroll
        for (int u = 0; u < 4; ++u) {
            const int tau = 4 * tj + u;
            const bool pf = (tau + 1 < NT);
            if (pf) load_pair(2 * tau + 3);          // prefetch in flight
            const int sa = (2 * u + 2) % RING;       // LDS slot of plane 2tau+1
            const int sb = (2 * u + 3) % RING;       // LDS slot of plane 2tau+2
            if ((u & 1) == 0) {
                make_partial(sa, P2);                // plane 2tau+1
                make_partial(sb, P3);                // plane 2tau+2
                combine(P0, P1, P2);                 // output d = 2tau
                combine(P1, P2, P3);                 // output d = 2tau+1
            } else {
                make_partial(sa, P0);
                make_partial(sb, P1);
                combine(P2, P3, P0);
                combine(P3, P0, P1);
            }
            if (pf) store_pair(2 * tau + 3);         // publish after compute
            __syncthreads();
        }
    }

    // ---- block reduction (reuse ring[0..3] as wave-sum scratch) ----
#pragma unroll
    for (int off = 32; off > 0; off >>= 1)
        acc += __shfl_down(acc, off, 64);
    if ((tid & 63) == 0) ring[tid >> 6] = acc;
    __syncthreads();
    if (tid == 0) {
        const float s = ring[0] + ring[1] + ring[2] + ring[3];
        atomicAdd(out, s * INV_COUNT);
    }
}

extern "C" void kernel_launch(void* const* d_in, const int* in_sizes, int n_in,
                              void* d_out, int out_size, void* d_ws, size_t ws_size,
                              hipStream_t stream) {
    const float* pred   = (const float*)d_in[0];
    const float* target = (const float*)d_in[1];
    float* out = (float*)d_out;

    zero_out_kernel<<<1, 64, 0, stream>>>(out);

    // 16 volumes * 4 d-quarters * 16 h-tiles = 1024 blocks
    const int nblocks = NB * NQ * (HH / TH);
    sobel_l1_kernel<<<nblocks, 256, 0, stream>>>(pred, target, out);
}

// Round 5
// 156.708 us; speedup vs baseline: 1.3329x; 1.3329x over previous
//
#include <hip/hip_runtime.h>

// pred/target (4,4,64,128,128) fp32 -> 16 volumes of 64x128x128.
#define NB 16
#define DD 64
#define HH 128
#define WW 128
#define HW (HH * WW)

constexpr int TROWS = 16;              // h-rows per block (256 thr = 16 rows x 16 strips)
constexpr int NQ = 8;                  // d-octants per volume
constexpr int QP = DD / NQ;            // 8 output planes per octant
constexpr float INV_COUNT = 1.0f / 50331648.0f; // 1/(3*16*64*128*128)

__global__ void zero_out_kernel(float* out) {
    if (threadIdx.x == 0 && blockIdx.x == 0) out[0] = 0.0f;
}

// ---- straight-line macros: named float4s only (R3 spill lesson) ----
// Variadic forwarding shims so SLOTn arguments expand BEFORE parameter
// matching (R4 lesson: macro args are counted before expansion).

// w-direction partials for one row of 8 outputs.
// RS = [1,2,1]-smoothed, RW = [-1,0,1]-difference.
#define ROWPART(D0, D1, LM, RP, RSa, RSb, RWa, RWb)                         \
    RSa.x = (LM)   + 2.f*D0.x + D0.y;  RSa.y = D0.x + 2.f*D0.y + D0.z;      \
    RSa.z = D0.y + 2.f*D0.z + D0.w;    RSa.w = D0.z + 2.f*D0.w + D1.x;      \
    RSb.x = D0.w + 2.f*D1.x + D1.y;    RSb.y = D1.x + 2.f*D1.y + D1.z;      \
    RSb.z = D1.y + 2.f*D1.z + D1.w;    RSb.w = D1.z + 2.f*D1.w + (RP);      \
    RWa.x = D0.y - (LM);   RWa.y = D0.z - D0.x;                             \
    RWa.z = D0.w - D0.y;   RWa.w = D1.x - D0.z;                             \
    RWb.x = D1.y - D0.w;   RWb.y = D1.z - D1.x;                             \
    RWb.z = D1.w - D1.y;   RWb.w = (RP) - D1.z;

#define DIFF4(D, A, B, F)                                                   \
    D.x = (A.x - B.x) * (F); D.y = (A.y - B.y) * (F);                       \
    D.z = (A.z - B.z) * (F); D.w = (A.w - B.w) * (F);

// Compute plane partials for plane d0+REL into slot (Aa,Ab,Ha,Hb,Wa,Wb).
// A = s(h)s(w)v, H = d(h)s(w)v, W = s(h)d(w)v.  MD = plane validity mask.
#define PARTIALS(...) PARTIALS_IMPL(__VA_ARGS__)
#define PARTIALS_IMPL(REL, MD, Aa, Ab, Ha, Hb, Wa, Wb) do {                 \
    const int pc_ = min(max(d0 + (REL), 0), DD - 1);                        \
    const float* pp_ = pred   + nbase + (size_t)pc_ * HW;                   \
    const float* pt_ = target + nbase + (size_t)pc_ * HW;                   \
    const float4 am0_ = *(const float4*)(pp_ + ro_m);                       \
    const float4 am1_ = *(const float4*)(pp_ + ro_m + 4);                   \
    const float4 a00_ = *(const float4*)(pp_ + ro_0);                       \
    const float4 a01_ = *(const float4*)(pp_ + ro_0 + 4);                   \
    const float4 ap0_ = *(const float4*)(pp_ + ro_p);                       \
    const float4 ap1_ = *(const float4*)(pp_ + ro_p + 4);                   \
    const float4 bm0_ = *(const float4*)(pt_ + ro_m);                       \
    const float4 bm1_ = *(const float4*)(pt_ + ro_m + 4);                   \
    const float4 b00_ = *(const float4*)(pt_ + ro_0);                       \
    const float4 b01_ = *(const float4*)(pt_ + ro_0 + 4);                   \
    const float4 bp0_ = *(const float4*)(pt_ + ro_p);                       \
    const float4 bp1_ = *(const float4*)(pt_ + ro_p + 4);                   \
    const float fm_ = mr_m * (MD), f0_ = (MD), fp_ = mr_p * (MD);           \
    float4 dm0_, dm1_, d00_, d01_, dp0_, dp1_;                              \
    DIFF4(dm0_, am0_, bm0_, fm_) DIFF4(dm1_, am1_, bm1_, fm_)               \
    DIFF4(d00_, a00_, b00_, f0_) DIFF4(d01_, a01_, b01_, f0_)               \
    DIFF4(dp0_, ap0_, bp0_, fp_) DIFF4(dp1_, ap1_, bp1_, fp_)               \
    const float lmm_ = __shfl_up(dm1_.w, 1, 16) * lmask;                    \
    const float rpm_ = __shfl_down(dm0_.x, 1, 16) * rmask;                  \
    const float lm0_ = __shfl_up(d01_.w, 1, 16) * lmask;                    \
    const float rp0_ = __shfl_down(d00_.x, 1, 16) * rmask;                  \
    const float lmp_ = __shfl_up(dp1_.w, 1, 16) * lmask;                    \
    const float rpp_ = __shfl_down(dp0_.x, 1, 16) * rmask;                  \
    float4 sma_, smb_, wma_, wmb_;                                          \
    float4 s0a_, s0b_, w0a_, w0b_;                                          \
    float4 spa_, spb_, wpa_, wpb_;                                          \
    ROWPART(dm0_, dm1_, lmm_, rpm_, sma_, smb_, wma_, wmb_)                 \
    ROWPART(d00_, d01_, lm0_, rp0_, s0a_, s0b_, w0a_, w0b_)                 \
    ROWPART(dp0_, dp1_, lmp_, rpp_, spa_, spb_, wpa_, wpb_)                 \
    Aa.x = sma_.x + 2.f*s0a_.x + spa_.x;  Aa.y = sma_.y + 2.f*s0a_.y + spa_.y; \
    Aa.z = sma_.z + 2.f*s0a_.z + spa_.z;  Aa.w = sma_.w + 2.f*s0a_.w + spa_.w; \
    Ab.x = smb_.x + 2.f*s0b_.x + spb_.x;  Ab.y = smb_.y + 2.f*s0b_.y + spb_.y; \
    Ab.z = smb_.z + 2.f*s0b_.z + spb_.z;  Ab.w = smb_.w + 2.f*s0b_.w + spb_.w; \
    Ha.x = spa_.x - sma_.x;  Ha.y = spa_.y - sma_.y;                        \
    Ha.z = spa_.z - sma_.z;  Ha.w = spa_.w - sma_.w;                        \
    Hb.x = spb_.x - smb_.x;  Hb.y = spb_.y - smb_.y;                        \
    Hb.z = spb_.z - smb_.z;  Hb.w = spb_.w - smb_.w;                        \
    Wa.x = wma_.x + 2.f*w0a_.x + wpa_.x;  Wa.y = wma_.y + 2.f*w0a_.y + wpa_.y; \
    Wa.z = wma_.z + 2.f*w0a_.z + wpa_.z;  Wa.w = wma_.w + 2.f*w0a_.w + wpa_.w; \
    Wb.x = wmb_.x + 2.f*w0b_.x + wpb_.x;  Wb.y = wmb_.y + 2.f*w0b_.y + wpb_.y; \
    Wb.z = wmb_.z + 2.f*w0b_.z + wpb_.z;  Wb.w = wmb_.w + 2.f*w0b_.w + wpb_.w; \
} while (0)

// Emit one output plane: slots S0/S1/S2 hold planes p-1 / p / p+1.
// out_d = A(p+1)-A(p-1); out_h = H0+2H1+H2; out_w = W0+2W1+W2.
#define EMIT(...) EMIT_IMPL(__VA_ARGS__)
#define EMIT_IMPL(A0a,A0b,H0a,H0b,W0a,W0b, A1a,A1b,H1a,H1b,W1a,W1b, A2a,A2b,H2a,H2b,W2a,W2b) do { \
    acc += fabsf(A2a.x - A0a.x) + fabsf(A2a.y - A0a.y)                      \
         + fabsf(A2a.z - A0a.z) + fabsf(A2a.w - A0a.w);                     \
    acc += fabsf(A2b.x - A0b.x) + fabsf(A2b.y - A0b.y)                      \
         + fabsf(A2b.z - A0b.z) + fabsf(A2b.w - A0b.w);                     \
    acc += fabsf(H0a.x + 2.f*H1a.x + H2a.x) + fabsf(H0a.y + 2.f*H1a.y + H2a.y) \
         + fabsf(H0a.z + 2.f*H1a.z + H2a.z) + fabsf(H0a.w + 2.f*H1a.w + H2a.w); \
    acc += fabsf(H0b.x + 2.f*H1b.x + H2b.x) + fabsf(H0b.y + 2.f*H1b.y + H2b.y) \
         + fabsf(H0b.z + 2.f*H1b.z + H2b.z) + fabsf(H0b.w + 2.f*H1b.w + H2b.w); \
    acc += fabsf(W0a.x + 2.f*W1a.x + W2a.x) + fabsf(W0a.y + 2.f*W1a.y + W2a.y) \
         + fabsf(W0a.z + 2.f*W1a.z + W2a.z) + fabsf(W0a.w + 2.f*W1a.w + W2a.w); \
    acc += fabsf(W0b.x + 2.f*W1b.x + W2b.x) + fabsf(W0b.y + 2.f*W1b.y + W2b.y) \
         + fabsf(W0b.z + 2.f*W1b.z + W2b.z) + fabsf(W0b.w + 2.f*W1b.w + W2b.w); \
} while (0)

#define SLOT0 c0Aa,c0Ab,c0Ha,c0Hb,c0Wa,c0Wb
#define SLOT1 c1Aa,c1Ab,c1Ha,c1Hb,c1Wa,c1Wb
#define SLOT2 c2Aa,c2Ab,c2Ha,c2Hb,c2Wa,c2Wb

__global__ __launch_bounds__(256) void sobel_l1_kernel(
    const float* __restrict__ pred,
    const float* __restrict__ target,
    float* __restrict__ out)
{
    __shared__ float wsum[4];          // only LDS use: final block reduction

    const int tid = threadIdx.x;
    int b = blockIdx.x;                // 1024 blocks: 8 h-tiles x 8 octants x 16 vol
    const int bh = b & 7;  b >>= 3;
    const int q  = b & 7;  b >>= 3;
    const int bn = b;

    const int row = tid >> 4;          // 0..15 (own h-row, always in range)
    const int sc  = tid & 15;          // w-strip (8 floats each)
    const int gh  = bh * TROWS + row;
    const int d0  = q * QP;
    const size_t nbase = (size_t)bn * (size_t)(DD * HW);

    const int wq   = sc * 8;
    const int ro_m = max(gh - 1, 0) * WW + wq;      // row above (clamped addr)
    const int ro_0 = gh * WW + wq;                  // own row
    const int ro_p = min(gh + 1, HH - 1) * WW + wq; // row below (clamped addr)
    const float mr_m = (gh - 1 >= 0) ? 1.f : 0.f;   // zero-pad masks (h)
    const float mr_p = (gh + 1 < HH) ? 1.f : 0.f;
    const float lmask = (sc == 0)  ? 0.f : 1.f;     // zero-pad masks (w)
    const float rmask = (sc == 15) ? 0.f : 1.f;
    const float mdA = (q == 0)      ? 0.f : 1.f;    // zero-pad masks (d)
    const float mdB = (q == NQ - 1) ? 0.f : 1.f;

    float acc = 0.f;

    // 3-slot register ring of plane partials (all named float4s).
    float4 c0Aa, c0Ab, c0Ha, c0Hb, c0Wa, c0Wb;
    float4 c1Aa, c1Ab, c1Ha, c1Hb, c1Wa, c1Wb;
    float4 c2Aa, c2Ab, c2Ha, c2Hb, c2Wa, c2Wb;

    // 10 plane steps (rel = -1..8), 8 output planes. No barriers anywhere.
    PARTIALS(-1, mdA, SLOT0);
    PARTIALS( 0, 1.f, SLOT1);
    PARTIALS( 1, 1.f, SLOT2);  EMIT(SLOT0, SLOT1, SLOT2);   // out d0+0
    PARTIALS( 2, 1.f, SLOT0);  EMIT(SLOT1, SLOT2, SLOT0);   // out d0+1
    PARTIALS( 3, 1.f, SLOT1);  EMIT(SLOT2, SLOT0, SLOT1);   // out d0+2
    PARTIALS( 4, 1.f, SLOT2);  EMIT(SLOT0, SLOT1, SLOT2);   // out d0+3
    PARTIALS( 5, 1.f, SLOT0);  EMIT(SLOT1, SLOT2, SLOT0);   // out d0+4
    PARTIALS( 6, 1.f, SLOT1);  EMIT(SLOT2, SLOT0, SLOT1);   // out d0+5
    PARTIALS( 7, 1.f, SLOT2);  EMIT(SLOT0, SLOT1, SLOT2);   // out d0+6
    PARTIALS( 8, mdB, SLOT0);  EMIT(SLOT1, SLOT2, SLOT0);   // out d0+7

    // ---- block reduction ----
#pragma unroll
    for (int off = 32; off > 0; off >>= 1)
        acc += __shfl_down(acc, off, 64);
    if ((tid & 63) == 0) wsum[tid >> 6] = acc;
    __syncthreads();
    if (tid == 0) {
        const float s = wsum[0] + wsum[1] + wsum[2] + wsum[3];
        atomicAdd(out, s * INV_COUNT);
    }
}

extern "C" void kernel_launch(void* const* d_in, const int* in_sizes, int n_in,
                              void* d_out, int out_size, void* d_ws, size_t ws_size,
                              hipStream_t stream) {
    const float* pred   = (const float*)d_in[0];
    const float* target = (const float*)d_in[1];
    float* out = (float*)d_out;

    zero_out_kernel<<<1, 64, 0, stream>>>(out);

    // 16 volumes * 8 d-octants * 8 h-tiles = 1024 blocks
    const int nblocks = NB * NQ * (HH / TROWS);
    sobel_l1_kernel<<<nblocks, 256, 0, stream>>>(pred, target, out);
}